// Round 1
// baseline (1180.004 us; speedup 1.0000x reference)
//
#include <hip/hip_runtime.h>
#include <cmath>

#define V_NODES  1000000
#define NODE_DIM 128
#define HIDDEN   128
#define OUT_DIM  128
#define GDIM     64
#define NGRAPH   50000

typedef unsigned short u16;
typedef __attribute__((ext_vector_type(8))) short          short8;
typedef __attribute__((ext_vector_type(8))) unsigned short ushort8;
typedef __attribute__((ext_vector_type(8))) __bf16         bf16x8;
typedef __attribute__((ext_vector_type(4))) float          f32x4;

__device__ __forceinline__ u16 f2bf(float f) {
  unsigned u = __builtin_bit_cast(unsigned, f);
  u += 0x7fff + ((u >> 16) & 1);   // RTNE
  return (u16)(u >> 16);
}

__device__ __forceinline__ f32x4 mfma_bf16(bf16x8 a, bf16x8 b, f32x4 c) {
  return __builtin_amdgcn_mfma_f32_16x16x32_bf16(a, b, c, 0, 0, 0);
}

// ---------- prep: weights -> bf16 in ws ----------
__global__ __launch_bounds__(256) void convert_weights(
    const float* __restrict__ W1, const float* __restrict__ W2,
    const float* __restrict__ W3,
    u16* __restrict__ w1b, u16* __restrict__ w2b, u16* __restrict__ w3b) {
  int i = blockIdx.x * 256 + threadIdx.x;
  if (i < NODE_DIM * HIDDEN) {
    w1b[i] = f2bf(W1[i]);
    w2b[i] = f2bf(W2[i]);
  }
  if (i < OUT_DIM * (2 * HIDDEN + GDIM)) w3b[i] = f2bf(W3[i]);
}

// ---------- counting sort of nodes by graph ----------
// count: histogram (this IS the `counts` tensor needed for the mean)
__global__ __launch_bounds__(256) void count_k(
    const int* __restrict__ n2g, int* __restrict__ cnt) {
  int i = blockIdx.x * 256 + threadIdx.x;
  if (i < V_NODES) atomicAdd(&cnt[n2g[i]], 1);
}

// exclusive scan over 50k counts, single block of 1024 (49 elems/thread)
__global__ __launch_bounds__(1024) void scan_k(
    const int* __restrict__ cnt, int* __restrict__ head) {
  __shared__ int ls[1024];
  const int t = threadIdx.x;
  const int base = t * 49;
  int s = 0;
#pragma unroll 7
  for (int j = 0; j < 49; ++j) {
    int idx = base + j;
    if (idx < NGRAPH) s += cnt[idx];
  }
  ls[t] = s;
  __syncthreads();
  for (int d = 1; d < 1024; d <<= 1) {
    int v = (t >= d) ? ls[t - d] : 0;
    __syncthreads();
    ls[t] += v;
    __syncthreads();
  }
  int run = ls[t] - s;  // exclusive prefix
#pragma unroll 7
  for (int j = 0; j < 49; ++j) {
    int idx = base + j;
    if (idx < NGRAPH) {
      head[idx] = run;
      run += cnt[idx];
    }
  }
}

// scatter: ord[pos] = node id (grouped by graph), gs[pos] = graph id
__global__ __launch_bounds__(256) void scatter_k(
    const int* __restrict__ n2g, int* __restrict__ head,
    int* __restrict__ ord, u16* __restrict__ gs) {
  int i = blockIdx.x * 256 + threadIdx.x;
  if (i < V_NODES) {
    int g = n2g[i];
    int pos = atomicAdd(&head[g], 1);
    ord[pos] = i;
    gs[pos] = (u16)g;   // NGRAPH = 50000 < 65536
  }
}

// ---------- fused gated MLP on sorted nodes + run-compressed scatter ----------
// block = 256 threads = 4 waves; block handles 64 *sorted positions* (wave: 16).
// MFMA core identical to the proven streaming version; A-rows gathered by ord.
// Epilogue: in-register segmented reduction over the wave's 16 sorted rows
// (quad-local chain + cross-quad shfl carry) -> ~1.75 atomic flushes per
// 16 rows per column instead of 16 (lane-atomics 128M -> ~14M).
__global__ __launch_bounds__(256, 2) void gather_gated(
    const float* __restrict__ x, const int* __restrict__ ord,
    const u16* __restrict__ gs,
    const u16* __restrict__ w1b, const u16* __restrict__ w2b,
    const float* __restrict__ b1, const float* __restrict__ b2,
    float* __restrict__ Z1) {
  extern __shared__ u16 lds[];
  u16* sW1 = lds;          // 16384 elems
  u16* sW2 = lds + 16384;  // 16384 elems
  const int tid = threadIdx.x;

  // stage 2x32KB bf16 weights, 16B chunks XOR-swizzled by (row&15)
#pragma unroll
  for (int i = 0; i < 8; ++i) {
    int m = i * 256 + tid;               // 16-byte chunk id, 0..2047
    int n = m >> 4, c = m & 15;
    int p = c ^ (n & 15);
    *(ushort8*)(sW1 + n * 128 + p * 8) = *(const ushort8*)(w1b + m * 8);
    *(ushort8*)(sW2 + n * 128 + p * 8) = *(const ushort8*)(w2b + m * 8);
  }
  __syncthreads();

  const int lane = tid & 63;
  const int wv   = tid >> 6;
  const int q    = lane >> 4;   // quad
  const int mr   = lane & 15;
  const int rowbase = blockIdx.x * 64 + wv * 16;
  const int node    = ord[rowbase + mr];   // gathered A-row

  f32x4 acc1[8] = {};
  f32x4 acc2[8] = {};

#pragma unroll
  for (int kc = 0; kc < 4; ++kc) {
    const int k0 = kc * 32;
    // A fragment: x[node][k0 + q*8 + j], fp32 -> bf16 (row is 512B contiguous;
    // a quad reads a 128B segment -> gather-friendly granularity)
    const float* ap = x + (size_t)node * NODE_DIM + k0 + q * 8;
    float4 a0 = *(const float4*)ap;
    float4 a1 = *(const float4*)(ap + 4);
    bf16x8 af;
    af[0] = (__bf16)a0.x; af[1] = (__bf16)a0.y; af[2] = (__bf16)a0.z; af[3] = (__bf16)a0.w;
    af[4] = (__bf16)a1.x; af[5] = (__bf16)a1.y; af[6] = (__bf16)a1.z; af[7] = (__bf16)a1.w;

    const int p = ((k0 >> 3) + q) ^ mr;  // swizzled chunk
#pragma unroll
    for (int t = 0; t < 8; ++t) {
      const int n = t * 16 + mr;
      short8 bs1 = *(const short8*)(sW1 + n * 128 + p * 8);
      short8 bs2 = *(const short8*)(sW2 + n * 128 + p * 8);
      acc1[t] = mfma_bf16(af, __builtin_bit_cast(bf16x8, bs1), acc1[t]);
      acc2[t] = mfma_bf16(af, __builtin_bit_cast(bf16x8, bs2), acc2[t]);
    }
  }

  // ---- epilogue: segmented run reduction over 16 sorted rows per wave ----
  // quad q owns rows rb4..rb4+3 (sorted positions); g values are quad-uniform
  const int rb4 = rowbase + q * 4;
  const int gq0 = gs[rb4 + 0];
  const int gq1 = gs[rb4 + 1];
  const int gq2 = gs[rb4 + 2];
  const int gq3 = gs[rb4 + 3];
  const int gprev = (q > 0) ? (int)gs[rb4 - 1] : -1;  // row before quad
  const int gnext = (q < 3) ? (int)gs[rb4 + 4] : -1;  // row after quad (-1 => forced flush at wave end)

  // flags for the cross-quad carry chain (t-independent)
  const int uni_own  = (gq0 == gq1) & (gq1 == gq2) & (gq2 == gq3);
  const int conn_own = (gq0 == gprev) ? 1 : 0;         // run continues from prev quad
  const int conn_p   = __shfl_up(conn_own, 16, 64);    // conn(q-1)
  const int uni_p    = __shfl_up(uni_own, 16, 64);     // uniform(q-1)
  const int conn_p2  = __shfl_up(conn_own, 32, 64);    // conn(q-2)
  const int uni_p2   = __shfl_up(uni_own, 32, 64);     // uniform(q-2)
  const bool c1 = conn_own != 0;
  const bool c2 = c1 && (uni_p  && conn_p);
  const bool c3 = c2 && (uni_p2 && conn_p2);

#pragma unroll
  for (int t = 0; t < 8; ++t) {
    const int col = t * 16 + mr;
    const float bb1 = b1[col];
    const float bb2 = b2[col];

    float l1, l2;
    l1 = acc1[t][0] + bb1; l2 = acc2[t][0] + bb2; const float h0 = l1 / (1.0f + __expf(-l2));
    l1 = acc1[t][1] + bb1; l2 = acc2[t][1] + bb2; const float h1 = l1 / (1.0f + __expf(-l2));
    l1 = acc1[t][2] + bb1; l2 = acc2[t][2] + bb2; const float h2 = l1 / (1.0f + __expf(-l2));
    l1 = acc1[t][3] + bb1; l2 = acc2[t][3] + bb2; const float h3 = l1 / (1.0f + __expf(-l2));

    // local trailing-run sum of this quad (no carry)
    float ts = h3;
    if (gq2 == gq3) { ts += h2; if (gq1 == gq3) { ts += h1; if (gq0 == gq3) ts += h0; } }
    const float ts1 = __shfl_up(ts, 16, 64);
    const float ts2 = __shfl_up(ts, 32, 64);
    const float ts3 = __shfl_up(ts, 48, 64);
    float carry = 0.0f;
    if (c1) { carry = ts1; if (c2) { carry += ts2; if (c3) carry += ts3; } }

    // chain through the quad's 4 rows, flushing at run boundaries.
    // A run is flushed by the quad containing its END (carry holds the
    // contribution of preceding quads). Wave end forces a flush.
    float run = carry + h0;
    if (gq1 != gq0) { atomicAdd(Z1 + (size_t)gq0 * HIDDEN + col, run); run = h1; } else run += h1;
    if (gq2 != gq1) { atomicAdd(Z1 + (size_t)gq1 * HIDDEN + col, run); run = h2; } else run += h2;
    if (gq3 != gq2) { atomicAdd(Z1 + (size_t)gq2 * HIDDEN + col, run); run = h3; } else run += h3;
    if (gnext != gq3) atomicAdd(Z1 + (size_t)gq3 * HIDDEN + col, run);
  }
}

// ---------- readout: relu([Z1, Z1/cnt, gx] @ W3^T + b3) ----------
__global__ __launch_bounds__(256, 4) void readout_k(
    const float* __restrict__ Z1, const int* __restrict__ cnt,
    const float* __restrict__ gx, const u16* __restrict__ w3b,
    const float* __restrict__ b3, float* __restrict__ out) {
  const int tid  = threadIdx.x;
  const int lane = tid & 63;
  const int wv   = tid >> 6;
  const int q    = lane >> 4;
  const int mr   = lane & 15;
  const int rowbase = blockIdx.x * 64 + wv * 16;
  const int arow    = rowbase + mr;
  const bool rowok  = arow < NGRAPH;   // wave-uniform (NGRAPH % 16 == 0)

  float inv = 0.0f;
  if (rowok) inv = 1.0f / fmaxf((float)cnt[arow], 1.0f);

  f32x4 acc[8] = {};

#pragma unroll
  for (int kc = 0; kc < 10; ++kc) {
    const int k0 = kc * 32;
    float av[8];
    if (rowok) {
      if (k0 < 128) {
        const float* p = Z1 + (size_t)arow * HIDDEN + k0 + q * 8;
        float4 a0 = *(const float4*)p;
        float4 a1 = *(const float4*)(p + 4);
        av[0]=a0.x; av[1]=a0.y; av[2]=a0.z; av[3]=a0.w;
        av[4]=a1.x; av[5]=a1.y; av[6]=a1.z; av[7]=a1.w;
      } else if (k0 < 256) {
        const float* p = Z1 + (size_t)arow * HIDDEN + (k0 - 128) + q * 8;
        float4 a0 = *(const float4*)p;
        float4 a1 = *(const float4*)(p + 4);
        av[0]=a0.x*inv; av[1]=a0.y*inv; av[2]=a0.z*inv; av[3]=a0.w*inv;
        av[4]=a1.x*inv; av[5]=a1.y*inv; av[6]=a1.z*inv; av[7]=a1.w*inv;
      } else {
        const float* p = gx + (size_t)arow * GDIM + (k0 - 256) + q * 8;
        float4 a0 = *(const float4*)p;
        float4 a1 = *(const float4*)(p + 4);
        av[0]=a0.x; av[1]=a0.y; av[2]=a0.z; av[3]=a0.w;
        av[4]=a1.x; av[5]=a1.y; av[6]=a1.z; av[7]=a1.w;
      }
    } else {
#pragma unroll
      for (int j = 0; j < 8; ++j) av[j] = 0.0f;
    }
    bf16x8 af;
#pragma unroll
    for (int j = 0; j < 8; ++j) af[j] = (__bf16)av[j];

#pragma unroll
    for (int t = 0; t < 8; ++t) {
      const int n = t * 16 + mr;
      short8 bs = *(const short8*)(w3b + (size_t)n * (2 * HIDDEN + GDIM) + k0 + q * 8);
      acc[t] = mfma_bf16(af, __builtin_bit_cast(bf16x8, bs), acc[t]);
    }
  }

#pragma unroll
  for (int t = 0; t < 8; ++t) {
    const int col = t * 16 + mr;
    const float bb = b3[col];
#pragma unroll
    for (int r = 0; r < 4; ++r) {
      const int row = rowbase + q * 4 + r;
      if (row < NGRAPH)
        out[(size_t)row * OUT_DIM + col] = fmaxf(acc[t][r] + bb, 0.0f);
    }
  }
}

extern "C" void kernel_launch(void* const* d_in, const int* in_sizes, int n_in,
                              void* d_out, int out_size, void* d_ws, size_t ws_size,
                              hipStream_t stream) {
  const float* x   = (const float*)d_in[0];
  const int*   n2g = (const int*)d_in[1];
  const float* gx  = (const float*)d_in[2];
  const float* W1  = (const float*)d_in[3];
  const float* b1  = (const float*)d_in[4];
  const float* W2  = (const float*)d_in[5];
  const float* b2  = (const float*)d_in[6];
  const float* W3  = (const float*)d_in[7];
  const float* b3  = (const float*)d_in[8];
  float* out = (float*)d_out;

  // ws layout:
  //   [0,32768)              W1 bf16
  //   [32768,65536)          W2 bf16
  //   [65536,147456)         W3 bf16 (81920 B)
  //   [147456, +25.6MB)      Z1 fp32   (NGRAPH*128)
  //   +200KB                 cnt int32 (NGRAPH)      -- node histogram
  //   +200KB                 head int32 (NGRAPH)     -- scan output / scatter cursor
  //   +4MB                   ord int32 (V)           -- node ids sorted by graph
  //   +2MB                   gs  u16  (V)            -- graph id per sorted position
  char* ws = (char*)d_ws;
  u16*   w1b  = (u16*)(ws);
  u16*   w2b  = (u16*)(ws + 32768);
  u16*   w3b  = (u16*)(ws + 65536);
  float* Z1   = (float*)(ws + 147456);
  int*   cnt  = (int*)(ws + 147456 + (size_t)NGRAPH * HIDDEN * 4);
  int*   head = (int*)(ws + 147456 + (size_t)NGRAPH * HIDDEN * 4 + (size_t)NGRAPH * 4);
  int*   ord  = (int*)(ws + 147456 + (size_t)NGRAPH * HIDDEN * 4 + (size_t)NGRAPH * 8);
  u16*   gs   = (u16*)(ws + 147456 + (size_t)NGRAPH * HIDDEN * 4 + (size_t)NGRAPH * 8
                          + (size_t)V_NODES * 4);

  // zero Z1 + cnt (contiguous); head is fully written by scan_k
  hipMemsetAsync(ws + 147456, 0,
                 (size_t)NGRAPH * HIDDEN * 4 + (size_t)NGRAPH * 4, stream);

  convert_weights<<<160, 256, 0, stream>>>(W1, W2, W3, w1b, w2b, w3b);

  const int nb = (V_NODES + 255) / 256;
  count_k<<<nb, 256, 0, stream>>>(n2g, cnt);
  scan_k<<<1, 1024, 0, stream>>>(cnt, head);
  scatter_k<<<nb, 256, 0, stream>>>(n2g, head, ord, gs);

  gather_gated<<<V_NODES / 64, 256, 2 * 16384 * sizeof(u16), stream>>>(
      x, ord, gs, w1b, w2b, b1, b2, Z1);

  readout_k<<<(NGRAPH + 63) / 64, 256, 0, stream>>>(Z1, cnt, gx, w3b, b3, out);
}

// Round 2
// 1014.387 us; speedup vs baseline: 1.1633x; 1.1633x over previous
//
#include <hip/hip_runtime.h>
#include <cmath>

#define V_NODES  1000000
#define NODE_DIM 128
#define HIDDEN   128
#define OUT_DIM  128
#define GDIM     64
#define NGRAPH   50000

typedef unsigned short u16;
typedef __attribute__((ext_vector_type(8))) short          short8;
typedef __attribute__((ext_vector_type(8))) unsigned short ushort8;
typedef __attribute__((ext_vector_type(8))) __bf16         bf16x8;
typedef __attribute__((ext_vector_type(4))) float          f32x4;

__device__ __forceinline__ u16 f2bf(float f) {
  unsigned u = __builtin_bit_cast(unsigned, f);
  u += 0x7fff + ((u >> 16) & 1);   // RTNE
  return (u16)(u >> 16);
}

__device__ __forceinline__ f32x4 mfma_bf16(bf16x8 a, bf16x8 b, f32x4 c) {
  return __builtin_amdgcn_mfma_f32_16x16x32_bf16(a, b, c, 0, 0, 0);
}

// ---------- prep: weights -> bf16 in ws ----------
// W1/W2 are written PRE-SWIZZLED (16B chunk p of row-group n holds source
// chunk p^(n&15)) so the per-block LDS staging is a pure linear copy.
__global__ __launch_bounds__(256) void convert_weights(
    const float* __restrict__ W1, const float* __restrict__ W2,
    const float* __restrict__ W3,
    u16* __restrict__ w1s, u16* __restrict__ w2s, u16* __restrict__ w3b) {
  int i = blockIdx.x * 256 + threadIdx.x;
  if (i < NODE_DIM * HIDDEN) {
    int d = i >> 3, j = i & 7;
    int n = d >> 4, p = d & 15;
    int c = p ^ (n & 15);
    int src = n * 128 + c * 8 + j;
    w1s[i] = f2bf(W1[src]);
    w2s[i] = f2bf(W2[src]);
  }
  if (i < OUT_DIM * (2 * HIDDEN + GDIM)) w3b[i] = f2bf(W3[i]);
}

// ---------- counting sort of nodes by graph ----------
// histogram (this IS the `counts` tensor needed for the mean); 4 nodes/thread
__global__ __launch_bounds__(256) void count_k(
    const int* __restrict__ n2g, int* __restrict__ cnt) {
  int i = blockIdx.x * 256 + threadIdx.x;
  if (i * 4 < V_NODES) {
    int4 g = *(const int4*)(n2g + i * 4);
    atomicAdd(&cnt[g.x], 1);
    atomicAdd(&cnt[g.y], 1);
    atomicAdd(&cnt[g.z], 1);
    atomicAdd(&cnt[g.w], 1);
  }
}

// exclusive scan over 50k counts, single block of 1024 (49 elems/thread)
__global__ __launch_bounds__(1024) void scan_k(
    const int* __restrict__ cnt, int* __restrict__ head) {
  __shared__ int ls[1024];
  const int t = threadIdx.x;
  const int base = t * 49;
  int s = 0;
#pragma unroll 7
  for (int j = 0; j < 49; ++j) {
    int idx = base + j;
    if (idx < NGRAPH) s += cnt[idx];
  }
  ls[t] = s;
  __syncthreads();
  for (int d = 1; d < 1024; d <<= 1) {
    int v = (t >= d) ? ls[t - d] : 0;
    __syncthreads();
    ls[t] += v;
    __syncthreads();
  }
  int run = ls[t] - s;  // exclusive prefix
#pragma unroll 7
  for (int j = 0; j < 49; ++j) {
    int idx = base + j;
    if (idx < NGRAPH) {
      head[idx] = run;
      run += cnt[idx];
    }
  }
}

// scatter: ord[pos] = node id (grouped by graph); 4 nodes/thread; no gs array
__global__ __launch_bounds__(256) void scatter_k(
    const int* __restrict__ n2g, int* __restrict__ head,
    int* __restrict__ ord) {
  int i = blockIdx.x * 256 + threadIdx.x;
  if (i * 4 < V_NODES) {
    int4 g = *(const int4*)(n2g + i * 4);
    int base = i * 4;
    ord[atomicAdd(&head[g.x], 1)] = base;
    ord[atomicAdd(&head[g.y], 1)] = base + 1;
    ord[atomicAdd(&head[g.z], 1)] = base + 2;
    ord[atomicAdd(&head[g.w], 1)] = base + 3;
  }
}

// ---------- fused gated MLP on sorted nodes + run-compressed scatter ----------
// block = 512 threads = 8 waves; block handles 128 sorted positions (wave: 16).
// 64KB LDS -> 2 blocks/CU -> 16 waves/CU (2x round-1 occupancy).
// x gather + n2g gather issued BEFORE the staging barrier so their latency
// hides under the weight copy. Graph ids distributed by shfl (no gs array).
__global__ __launch_bounds__(512, 4) void gather_gated(
    const float* __restrict__ x, const int* __restrict__ ord,
    const int* __restrict__ n2g,
    const u16* __restrict__ w1s, const u16* __restrict__ w2s,
    const float* __restrict__ b1, const float* __restrict__ b2,
    float* __restrict__ Z1) {
  extern __shared__ u16 lds[];
  u16* sW1 = lds;          // 16384 elems
  u16* sW2 = lds + 16384;  // 16384 elems
  const int tid  = threadIdx.x;
  const int lane = tid & 63;
  const int wv   = tid >> 6;
  const int q    = lane >> 4;   // quad
  const int mr   = lane & 15;
  const int rowbase = blockIdx.x * 128 + wv * 16;
  const int rowpos  = rowbase + mr;
  const int rp      = rowpos < V_NODES ? rowpos : V_NODES - 1;

  const int node = ord[rp];    // issue gather chain ASAP

  // stage 2x32KB pre-swizzled weights: pure linear copy, 4 chunks each/thread
#pragma unroll
  for (int i = 0; i < 4; ++i) {
    int m = i * 512 + tid;
    *(ushort8*)(sW1 + m * 8) = *(const ushort8*)(w1s + m * 8);
    *(ushort8*)(sW2 + m * 8) = *(const ushort8*)(w2s + m * 8);
  }

  const int g_own = (rowpos < V_NODES) ? n2g[node] : -1;

  // prefetch the x row segments and convert to bf16 (pre-barrier)
  bf16x8 af[4];
#pragma unroll
  for (int kc = 0; kc < 4; ++kc) {
    const float* ap = x + (size_t)node * NODE_DIM + kc * 32 + q * 8;
    float4 a0 = *(const float4*)ap;
    float4 a1 = *(const float4*)(ap + 4);
    af[kc][0] = (__bf16)a0.x; af[kc][1] = (__bf16)a0.y;
    af[kc][2] = (__bf16)a0.z; af[kc][3] = (__bf16)a0.w;
    af[kc][4] = (__bf16)a1.x; af[kc][5] = (__bf16)a1.y;
    af[kc][6] = (__bf16)a1.z; af[kc][7] = (__bf16)a1.w;
  }

  // distribute graph ids of the wave's 16 rows (lane mr holds g(rowbase+mr))
  const int gq0 = __shfl(g_own, q * 4 + 0, 64);
  const int gq1 = __shfl(g_own, q * 4 + 1, 64);
  const int gq2 = __shfl(g_own, q * 4 + 2, 64);
  const int gq3 = __shfl(g_own, q * 4 + 3, 64);
  const int gpv = __shfl(g_own, (q * 4 - 1) & 63, 64);
  const int gnv = __shfl(g_own, (q * 4 + 4) & 15, 64);
  const int gprev = (q > 0) ? gpv : -1;   // wave start forces new run
  const int gnext = (q < 3) ? gnv : -1;   // wave end forces flush

  // flags for the cross-quad carry chain (t-independent)
  const int uni_own  = (gq0 == gq1) & (gq1 == gq2) & (gq2 == gq3);
  const int conn_own = (gq0 == gprev) ? 1 : 0;
  const int conn_p   = __shfl_up(conn_own, 16, 64);
  const int uni_p    = __shfl_up(uni_own, 16, 64);
  const int conn_p2  = __shfl_up(conn_own, 32, 64);
  const int uni_p2   = __shfl_up(uni_own, 32, 64);
  const bool c1 = conn_own != 0;
  const bool c2 = c1 && (uni_p  && conn_p);
  const bool c3 = c2 && (uni_p2 && conn_p2);

  __syncthreads();

  f32x4 acc1[8] = {};
  f32x4 acc2[8] = {};

#pragma unroll
  for (int kc = 0; kc < 4; ++kc) {
    const int p = (kc * 4 + q) ^ mr;  // swizzled chunk (n&15 == mr)
#pragma unroll
    for (int t = 0; t < 8; ++t) {
      const int n = t * 16 + mr;
      short8 bs1 = *(const short8*)(sW1 + n * 128 + p * 8);
      short8 bs2 = *(const short8*)(sW2 + n * 128 + p * 8);
      acc1[t] = mfma_bf16(af[kc], __builtin_bit_cast(bf16x8, bs1), acc1[t]);
      acc2[t] = mfma_bf16(af[kc], __builtin_bit_cast(bf16x8, bs2), acc2[t]);
    }
  }

  // ---- epilogue: segmented run reduction over 16 sorted rows per wave ----
#pragma unroll
  for (int t = 0; t < 8; ++t) {
    const int col = t * 16 + mr;
    const float bb1 = b1[col];
    const float bb2 = b2[col];

    float l1, l2;
    l1 = acc1[t][0] + bb1; l2 = acc2[t][0] + bb2; const float h0 = l1 / (1.0f + __expf(-l2));
    l1 = acc1[t][1] + bb1; l2 = acc2[t][1] + bb2; const float h1 = l1 / (1.0f + __expf(-l2));
    l1 = acc1[t][2] + bb1; l2 = acc2[t][2] + bb2; const float h2 = l1 / (1.0f + __expf(-l2));
    l1 = acc1[t][3] + bb1; l2 = acc2[t][3] + bb2; const float h3 = l1 / (1.0f + __expf(-l2));

    // local trailing-run sum of this quad (no carry)
    float ts = h3;
    if (gq2 == gq3) { ts += h2; if (gq1 == gq3) { ts += h1; if (gq0 == gq3) ts += h0; } }
    const float ts1 = __shfl_up(ts, 16, 64);
    const float ts2 = __shfl_up(ts, 32, 64);
    const float ts3 = __shfl_up(ts, 48, 64);
    float carry = 0.0f;
    if (c1) { carry = ts1; if (c2) { carry += ts2; if (c3) carry += ts3; } }

    // chain through the quad's 4 rows, flushing at run boundaries.
    float run = carry + h0;
    if (gq1 != gq0) { if (gq0 >= 0) atomicAdd(Z1 + (size_t)gq0 * HIDDEN + col, run); run = h1; } else run += h1;
    if (gq2 != gq1) { if (gq1 >= 0) atomicAdd(Z1 + (size_t)gq1 * HIDDEN + col, run); run = h2; } else run += h2;
    if (gq3 != gq2) { if (gq2 >= 0) atomicAdd(Z1 + (size_t)gq2 * HIDDEN + col, run); run = h3; } else run += h3;
    if (gnext != gq3) { if (gq3 >= 0) atomicAdd(Z1 + (size_t)gq3 * HIDDEN + col, run); }
  }
}

// ---------- readout: relu([Z1, Z1/cnt, gx] @ W3^T + b3) ----------
__global__ __launch_bounds__(256, 4) void readout_k(
    const float* __restrict__ Z1, const int* __restrict__ cnt,
    const float* __restrict__ gx, const u16* __restrict__ w3b,
    const float* __restrict__ b3, float* __restrict__ out) {
  const int tid  = threadIdx.x;
  const int lane = tid & 63;
  const int wv   = tid >> 6;
  const int q    = lane >> 4;
  const int mr   = lane & 15;
  const int rowbase = blockIdx.x * 64 + wv * 16;
  const int arow    = rowbase + mr;
  const bool rowok  = arow < NGRAPH;   // wave-uniform (NGRAPH % 16 == 0)

  float inv = 0.0f;
  if (rowok) inv = 1.0f / fmaxf((float)cnt[arow], 1.0f);

  f32x4 acc[8] = {};

#pragma unroll
  for (int kc = 0; kc < 10; ++kc) {
    const int k0 = kc * 32;
    float av[8];
    if (rowok) {
      if (k0 < 128) {
        const float* p = Z1 + (size_t)arow * HIDDEN + k0 + q * 8;
        float4 a0 = *(const float4*)p;
        float4 a1 = *(const float4*)(p + 4);
        av[0]=a0.x; av[1]=a0.y; av[2]=a0.z; av[3]=a0.w;
        av[4]=a1.x; av[5]=a1.y; av[6]=a1.z; av[7]=a1.w;
      } else if (k0 < 256) {
        const float* p = Z1 + (size_t)arow * HIDDEN + (k0 - 128) + q * 8;
        float4 a0 = *(const float4*)p;
        float4 a1 = *(const float4*)(p + 4);
        av[0]=a0.x*inv; av[1]=a0.y*inv; av[2]=a0.z*inv; av[3]=a0.w*inv;
        av[4]=a1.x*inv; av[5]=a1.y*inv; av[6]=a1.z*inv; av[7]=a1.w*inv;
      } else {
        const float* p = gx + (size_t)arow * GDIM + (k0 - 256) + q * 8;
        float4 a0 = *(const float4*)p;
        float4 a1 = *(const float4*)(p + 4);
        av[0]=a0.x; av[1]=a0.y; av[2]=a0.z; av[3]=a0.w;
        av[4]=a1.x; av[5]=a1.y; av[6]=a1.z; av[7]=a1.w;
      }
    } else {
#pragma unroll
      for (int j = 0; j < 8; ++j) av[j] = 0.0f;
    }
    bf16x8 af;
#pragma unroll
    for (int j = 0; j < 8; ++j) af[j] = (__bf16)av[j];

#pragma unroll
    for (int t = 0; t < 8; ++t) {
      const int n = t * 16 + mr;
      short8 bs = *(const short8*)(w3b + (size_t)n * (2 * HIDDEN + GDIM) + k0 + q * 8);
      acc[t] = mfma_bf16(af, __builtin_bit_cast(bf16x8, bs), acc[t]);
    }
  }

#pragma unroll
  for (int t = 0; t < 8; ++t) {
    const int col = t * 16 + mr;
    const float bb = b3[col];
#pragma unroll
    for (int r = 0; r < 4; ++r) {
      const int row = rowbase + q * 4 + r;
      if (row < NGRAPH)
        out[(size_t)row * OUT_DIM + col] = fmaxf(acc[t][r] + bb, 0.0f);
    }
  }
}

extern "C" void kernel_launch(void* const* d_in, const int* in_sizes, int n_in,
                              void* d_out, int out_size, void* d_ws, size_t ws_size,
                              hipStream_t stream) {
  const float* x   = (const float*)d_in[0];
  const int*   n2g = (const int*)d_in[1];
  const float* gx  = (const float*)d_in[2];
  const float* W1  = (const float*)d_in[3];
  const float* b1  = (const float*)d_in[4];
  const float* W2  = (const float*)d_in[5];
  const float* b2  = (const float*)d_in[6];
  const float* W3  = (const float*)d_in[7];
  const float* b3  = (const float*)d_in[8];
  float* out = (float*)d_out;

  // ws layout:
  //   [0,32768)              W1 bf16 (pre-swizzled)
  //   [32768,65536)          W2 bf16 (pre-swizzled)
  //   [65536,147456)         W3 bf16 (81920 B, linear)
  //   [147456, +25.6MB)      Z1 fp32   (NGRAPH*128)
  //   +200KB                 cnt int32 (NGRAPH)   -- node histogram
  //   +200KB                 head int32 (NGRAPH)  -- scan output / scatter cursor
  //   +4MB                   ord int32 (V)        -- node ids sorted by graph
  char* ws = (char*)d_ws;
  u16*   w1s  = (u16*)(ws);
  u16*   w2s  = (u16*)(ws + 32768);
  u16*   w3b  = (u16*)(ws + 65536);
  float* Z1   = (float*)(ws + 147456);
  int*   cnt  = (int*)(ws + 147456 + (size_t)NGRAPH * HIDDEN * 4);
  int*   head = (int*)(ws + 147456 + (size_t)NGRAPH * HIDDEN * 4 + (size_t)NGRAPH * 4);
  int*   ord  = (int*)(ws + 147456 + (size_t)NGRAPH * HIDDEN * 4 + (size_t)NGRAPH * 8);

  // zero Z1 + cnt (contiguous); head is fully written by scan_k
  hipMemsetAsync(ws + 147456, 0,
                 (size_t)NGRAPH * HIDDEN * 4 + (size_t)NGRAPH * 4, stream);

  convert_weights<<<160, 256, 0, stream>>>(W1, W2, W3, w1s, w2s, w3b);

  const int nb4 = (V_NODES / 4 + 255) / 256;
  count_k<<<nb4, 256, 0, stream>>>(n2g, cnt);
  scan_k<<<1, 1024, 0, stream>>>(cnt, head);
  scatter_k<<<nb4, 256, 0, stream>>>(n2g, head, ord);

  gather_gated<<<(V_NODES + 127) / 128, 512, 2 * 16384 * sizeof(u16), stream>>>(
      x, ord, n2g, w1s, w2s, b1, b2, Z1);

  readout_k<<<(NGRAPH + 63) / 64, 256, 0, stream>>>(Z1, cnt, gx, w3b, b3, out);
}